// Round 1
// baseline (973.645 us; speedup 1.0000x reference)
//
#include <hip/hip_runtime.h>
#include <math.h>

// Problem constants (fixed by reference)
#define N_NODES 50000
#define N_FEAT  500
#define DH      256
#define KC      16
#define NE      800000
#define KPAD    512     // N_FEAT padded to MFMA K multiple
#define MPAD    50048   // 391 * 128 (GEMM M tiles)
#define NB64    782     // ceil(N_NODES/64)

typedef __attribute__((ext_vector_type(8))) short short8;
typedef __attribute__((ext_vector_type(4))) float f32x4;

__device__ __forceinline__ unsigned short f2bf(float f) {
  unsigned u = __float_as_uint(f);
  u += 0x7FFFu + ((u >> 16) & 1u);   // RNE
  return (unsigned short)(u >> 16);
}

__device__ __forceinline__ float selu_f(float x) {
  return 1.0507009873554805f * (x > 0.f ? x : 1.6732632423543772f * expm1f(x));
}

__device__ __forceinline__ void gload16(const void* g, void* l) {
  __builtin_amdgcn_global_load_lds(
      (const __attribute__((address_space(1))) unsigned int*)g,
      (__attribute__((address_space(3))) unsigned int*)l, 16, 0, 0);
}

// ---- f32 -> bf16 with zero padding: in [rin][cin] -> out [rout][cout] ----
__global__ void k_cvt_pad(const float* __restrict__ in, unsigned short* __restrict__ out,
                          int rin, int cin, int rout, int cout) {
  const int cpairs = cout >> 1;
  const long total = (long)rout * cpairs;
  for (long idx = (long)blockIdx.x * blockDim.x + threadIdx.x; idx < total;
       idx += (long)gridDim.x * blockDim.x) {
    const int row = (int)(idx / cpairs);
    const int c2  = (int)(idx - (long)row * cpairs) * 2;
    float x = 0.f, y = 0.f;
    if (row < rin && c2 < cin) {   // cin even, so c2+1 < cin too
      const float2 v = *(const float2*)(in + (size_t)row * cin + c2);
      x = v.x; y = v.y;
    }
    ushort2 o; o.x = f2bf(x); o.y = f2bf(y);
    *(ushort2*)(out + (size_t)row * cout + c2) = o;
  }
}

// ---- bf16 GEMM: C[m][n] = sum_k A[m][k]*B[n][k]; A [MPAD][KPAD], B [DH][KPAD] ----
__global__ __launch_bounds__(256, 2) void k_gemm_bt(
    const unsigned short* __restrict__ A, const unsigned short* __restrict__ B,
    float* __restrict__ C) {
  __shared__ short As[128 * 64];
  __shared__ short Bs[128 * 64];
  const int t = threadIdx.x;
  const int lane = t & 63, wave = t >> 6;
  const int wr = (wave >> 1) * 64, wc = (wave & 1) * 64;
  const int bm = blockIdx.x * 128, bn = blockIdx.y * 128;
  const int lr = lane & 15, lk = (lane >> 4) * 8;
  f32x4 acc[4][4] = {};
  for (int kb = 0; kb < KPAD; kb += 64) {
#pragma unroll
    for (int i = 0; i < 4; ++i) {
      const int chunk = i * 256 + t;
      const int r = chunk >> 3, c8 = (chunk & 7) << 3;
      gload16(A + (size_t)(bm + r) * KPAD + kb + c8, (void*)(As + (size_t)chunk * 8));
      gload16(B + (size_t)(bn + r) * KPAD + kb + c8, (void*)(Bs + (size_t)chunk * 8));
    }
    __syncthreads();
#pragma unroll
    for (int kk = 0; kk < 64; kk += 32) {
      short8 af[4], bfr[4];
#pragma unroll
      for (int m = 0; m < 4; ++m)
        af[m] = *(const short8*)(As + (wr + m * 16 + lr) * 64 + kk + lk);
#pragma unroll
      for (int n = 0; n < 4; ++n)
        bfr[n] = *(const short8*)(Bs + (wc + n * 16 + lr) * 64 + kk + lk);
#pragma unroll
      for (int m = 0; m < 4; ++m)
#pragma unroll
        for (int n = 0; n < 4; ++n)
          acc[m][n] = __builtin_amdgcn_mfma_f32_16x16x32_bf16(af[m], bfr[n], acc[m][n], 0, 0, 0);
    }
    __syncthreads();
  }
  const int crow = (lane >> 4) * 4, ccol = lane & 15;
#pragma unroll
  for (int m = 0; m < 4; ++m)
#pragma unroll
    for (int n = 0; n < 4; ++n)
#pragma unroll
      for (int r = 0; r < 4; ++r)
        C[(size_t)(bm + wr + m * 16 + crow + r) * DH + (bn + wc + n * 16 + ccol)] = acc[m][n][r];
}

// ---- CSR build ----
__global__ void k_count(const int* __restrict__ row, int* __restrict__ counts) {
  const int e = blockIdx.x * blockDim.x + threadIdx.x;
  if (e < NE) atomicAdd(&counts[row[e]], 1);
}

__global__ __launch_bounds__(1024) void k_scan(const int* __restrict__ counts,
                                               int* __restrict__ row_ptr, int* __restrict__ cursor) {
  __shared__ int part[1024];
  const int t = threadIdx.x;
  const int per = (N_NODES + 1023) / 1024;
  const int base = t * per;
  int s = 0;
  for (int i = 0; i < per; ++i) { const int j = base + i; if (j < N_NODES) s += counts[j]; }
  part[t] = s;
  __syncthreads();
  for (int off = 1; off < 1024; off <<= 1) {
    const int v = (t >= off) ? part[t - off] : 0;
    __syncthreads();
    part[t] += v;
    __syncthreads();
  }
  int run = (t == 0) ? 0 : part[t - 1];
  for (int i = 0; i < per; ++i) {
    const int j = base + i;
    if (j < N_NODES) { row_ptr[j] = run; cursor[j] = run; run += counts[j]; }
  }
  if (t == 1023) row_ptr[N_NODES] = part[1023];
}

__global__ void k_scatter(const int* __restrict__ row, const int* __restrict__ col,
                          const float* __restrict__ gnv, int* __restrict__ cursor,
                          int* __restrict__ ecol, float* __restrict__ eval) {
  const int e = blockIdx.x * blockDim.x + threadIdx.x;
  if (e < NE) {
    const int p = atomicAdd(&cursor[row[e]], 1);
    ecol[p] = col[e];
    eval[p] = gnv[e];
  }
}

// ---- SpMM + selu (gcn pass): one wave per row, lane covers 4 cols ----
__global__ __launch_bounds__(256) void k_spmm_gcn(
    const int* __restrict__ row_ptr, const int* __restrict__ ecol, const float* __restrict__ eval,
    const float* __restrict__ XW, const float* __restrict__ b1, float* __restrict__ out) {
  const int wave = threadIdx.x >> 6, lane = threadIdx.x & 63;
  const int i = blockIdx.x * 4 + wave;
  const int c0 = lane * 4;
  const int s = row_ptr[i], e = row_ptr[i + 1];
  float ax = 0.f, ay = 0.f, az = 0.f, aw = 0.f;
  for (int p = s; p < e; ++p) {
    const float v = eval[p];
    const int c = ecol[p];
    const float4 x = *(const float4*)(XW + (size_t)c * DH + c0);
    ax += v * x.x; ay += v * x.y; az += v * x.z; aw += v * x.w;
  }
  const float4 b = *(const float4*)(b1 + c0);
  float4 o;
  o.x = selu_f(ax + b.x); o.y = selu_f(ay + b.y);
  o.z = selu_f(az + b.z); o.w = selu_f(aw + b.w);
  *(float4*)(out + (size_t)i * DH + c0) = o;
}

// ---- SpMM + selu (aug pass), fused epilogue: colSumAug partials + dot(aug,gcn) ----
__global__ __launch_bounds__(256) void k_spmm_aug(
    const int* __restrict__ row_ptr, const int* __restrict__ ecol, const float* __restrict__ eval,
    const float* __restrict__ XW, const float* __restrict__ b1, const float* __restrict__ gcn,
    float* __restrict__ augpart, float* __restrict__ dotAG) {
  __shared__ float colacc[DH];
  __shared__ float dacc;
  colacc[threadIdx.x] = 0.f;
  if (threadIdx.x == 0) dacc = 0.f;
  __syncthreads();
  const int wave = threadIdx.x >> 6, lane = threadIdx.x & 63;
  const int i = blockIdx.x * 4 + wave;
  const int c0 = lane * 4;
  const int s = row_ptr[i], e = row_ptr[i + 1];
  float ax = 0.f, ay = 0.f, az = 0.f, aw = 0.f;
  for (int p = s; p < e; ++p) {
    const float v = eval[p];
    const int c = ecol[p];
    const float4 x = *(const float4*)(XW + (size_t)c * DH + c0);
    ax += v * x.x; ay += v * x.y; az += v * x.z; aw += v * x.w;
  }
  const float4 b = *(const float4*)(b1 + c0);
  const float sx = selu_f(ax + b.x), sy = selu_f(ay + b.y);
  const float sz = selu_f(az + b.z), sw = selu_f(aw + b.w);
  const float4 g = *(const float4*)(gcn + (size_t)i * DH + c0);
  float d = sx * g.x + sy * g.y + sz * g.z + sw * g.w;
#pragma unroll
  for (int off = 32; off; off >>= 1) d += __shfl_xor(d, off);
  if (lane == 0) atomicAdd(&dacc, d);
  atomicAdd(&colacc[c0 + 0], sx);
  atomicAdd(&colacc[c0 + 1], sy);
  atomicAdd(&colacc[c0 + 2], sz);
  atomicAdd(&colacc[c0 + 3], sw);
  __syncthreads();
  atomicAdd(&augpart[(size_t)(blockIdx.x & 63) * DH + threadIdx.x], colacc[threadIdx.x]);
  if (threadIdx.x == 0) atomicAdd(dotAG, dacc);
}

// ---- assignments = softmax(gcn @ Wt^T + bt) : one wave per node ----
__global__ __launch_bounds__(256) void k_assign(const float* __restrict__ gcn,
                                                const float* __restrict__ Wt,
                                                const float* __restrict__ bt,
                                                float* __restrict__ S) {
  __shared__ float Wl[KC * DH];
  __shared__ float btl[KC];
  for (int i = threadIdx.x; i < KC * DH; i += 256) Wl[i] = Wt[i];
  if (threadIdx.x < KC) btl[threadIdx.x] = bt[threadIdx.x];
  __syncthreads();
  const int wave = threadIdx.x >> 6, lane = threadIdx.x & 63;
  const int c0 = lane * 4;
  for (int n = blockIdx.x * 4 + wave; n < N_NODES; n += gridDim.x * 4) {
    const float4 g = *(const float4*)(gcn + (size_t)n * DH + c0);
    float lg[KC];
#pragma unroll
    for (int k = 0; k < KC; ++k) {
      const float4 w = *(const float4*)(Wl + k * DH + c0);
      lg[k] = g.x * w.x + g.y * w.y + g.z * w.z + g.w * w.w;
    }
#pragma unroll
    for (int off = 32; off; off >>= 1)
#pragma unroll
      for (int k = 0; k < KC; ++k) lg[k] += __shfl_xor(lg[k], off);
    float mx = -3.4e38f;
#pragma unroll
    for (int k = 0; k < KC; ++k) { lg[k] += btl[k]; mx = fmaxf(mx, lg[k]); }
    float se = 0.f;
#pragma unroll
    for (int k = 0; k < KC; ++k) { lg[k] = expf(lg[k] - mx); se += lg[k]; }
    const float inv = 1.f / se;
    float myv = 0.f;
#pragma unroll
    for (int k = 0; k < KC; ++k) if (lane == k) myv = lg[k];   // static-index select
    if (lane < KC) S[(size_t)n * KC + lane] = myv * inv;
  }
}

// ---- cluster sizes: cs[k] = sum_n S[n,k] ----
__global__ void k_cs(const float* __restrict__ S, float* __restrict__ cs) {
  const int t = threadIdx.x;
  float local = 0.f;
  for (long idx = (long)blockIdx.x * 256 + t; idx < (long)N_NODES * KC; idx += (long)gridDim.x * 256)
    local += S[idx];
  __shared__ float red[256];
  red[t] = local;
  __syncthreads();
  if (t < KC) {
    float s = 0.f;
#pragma unroll
    for (int j = 0; j < 16; ++j) s += red[t + KC * j];
    atomicAdd(&cs[t], s);
  }
}

// ---- edge stats: tp = sum_e v*dot16(S[row],S[col]); nl[k] = sum_e v*S[col,k] ----
__global__ __launch_bounds__(256) void k_edge(const int* __restrict__ grow, const int* __restrict__ gcol,
                                              const float* __restrict__ gvals, const float* __restrict__ S,
                                              float* __restrict__ nl, float* __restrict__ tp) {
  float ltp = 0.f;
  float lnl[KC];
#pragma unroll
  for (int k = 0; k < KC; ++k) lnl[k] = 0.f;
  for (long e = (long)blockIdx.x * 256 + threadIdx.x; e < NE; e += (long)gridDim.x * 256) {
    const int r = grow[e], c = gcol[e];
    const float v = gvals[e];
    const float4* sr = (const float4*)(S + (size_t)r * KC);
    const float4* sc = (const float4*)(S + (size_t)c * KC);
    const float4 a0 = sr[0], a1 = sr[1], a2 = sr[2], a3 = sr[3];
    const float4 b0 = sc[0], b1v = sc[1], b2 = sc[2], b3 = sc[3];
    const float dot = a0.x * b0.x + a0.y * b0.y + a0.z * b0.z + a0.w * b0.w
                    + a1.x * b1v.x + a1.y * b1v.y + a1.z * b1v.z + a1.w * b1v.w
                    + a2.x * b2.x + a2.y * b2.y + a2.z * b2.z + a2.w * b2.w
                    + a3.x * b3.x + a3.y * b3.y + a3.z * b3.z + a3.w * b3.w;
    ltp += v * dot;
    lnl[0] += v * b0.x;  lnl[1] += v * b0.y;  lnl[2] += v * b0.z;  lnl[3] += v * b0.w;
    lnl[4] += v * b1v.x; lnl[5] += v * b1v.y; lnl[6] += v * b1v.z; lnl[7] += v * b1v.w;
    lnl[8] += v * b2.x;  lnl[9] += v * b2.y;  lnl[10] += v * b2.z; lnl[11] += v * b2.w;
    lnl[12] += v * b3.x; lnl[13] += v * b3.y; lnl[14] += v * b3.z; lnl[15] += v * b3.w;
  }
#pragma unroll
  for (int off = 32; off; off >>= 1) {
    ltp += __shfl_xor(ltp, off);
#pragma unroll
    for (int k = 0; k < KC; ++k) lnl[k] += __shfl_xor(lnl[k], off);
  }
  __shared__ float wred[4][KC + 1];
  const int wave = threadIdx.x >> 6, lane = threadIdx.x & 63;
  if (lane == 0) {
    wred[wave][0] = ltp;
#pragma unroll
    for (int k = 0; k < KC; ++k) wred[wave][1 + k] = lnl[k];
  }
  __syncthreads();
  if (threadIdx.x < KC + 1) {
    const float s = wred[0][threadIdx.x] + wred[1][threadIdx.x] + wred[2][threadIdx.x] + wred[3][threadIdx.x];
    if (threadIdx.x == 0) atomicAdd(tp, s);
    else atomicAdd(&nl[threadIdx.x - 1], s);
  }
}

// ---- column max / exp-sum partials over gcn_out (log_softmax axis=0) ----
__global__ void k_colmax_part(const float* __restrict__ g, float* __restrict__ pmax) {
  const int d = threadIdx.x;
  const int r0 = blockIdx.x * 64;
  const int r1 = min(r0 + 64, N_NODES);
  float m = -3.4e38f;
  for (int r = r0; r < r1; ++r) m = fmaxf(m, g[(size_t)r * DH + d]);
  pmax[(size_t)blockIdx.x * DH + d] = m;
}

__global__ void k_colmax_fin(const float* __restrict__ pmax, float* __restrict__ colmax) {
  const int d = threadIdx.x;
  float m = -3.4e38f;
  for (int b = 0; b < NB64; ++b) m = fmaxf(m, pmax[(size_t)b * DH + d]);
  colmax[d] = m;
}

__global__ void k_colexp_part(const float* __restrict__ g, const float* __restrict__ colmax,
                              float* __restrict__ psum) {
  const int d = threadIdx.x;
  const float cm = colmax[d];
  const int r0 = blockIdx.x * 64;
  const int r1 = min(r0 + 64, N_NODES);
  float s = 0.f;
  for (int r = r0; r < r1; ++r) s += expf(g[(size_t)r * DH + d] - cm);
  psum[(size_t)blockIdx.x * DH + d] = s;
}

// ---- final scalar assembly ----
// scal layout: [0]=dotAG, [1]=tp, [2..17]=nl, [18..33]=cs
__global__ void k_final(const float* __restrict__ psum, const float* __restrict__ colmax,
                        const float* __restrict__ augpart, const float* __restrict__ scal,
                        float* __restrict__ out) {
  const int d = threadIdx.x;
  float s = 0.f;
  for (int b = 0; b < NB64; ++b) s += psum[(size_t)b * DH + d];
  const float L = colmax[d] + logf(s);
  float sa = 0.f;
  for (int b = 0; b < 64; ++b) sa += augpart[(size_t)b * DH + d];
  __shared__ float red[DH];
  red[d] = L * sa;
  __syncthreads();
  for (int off = 128; off; off >>= 1) {
    if (d < off) red[d] += red[d + off];
    __syncthreads();
  }
  if (d == 0) {
    const float sumLA = red[0];
    const float dotAG = scal[0];
    const float tp = scal[1];
    float nl2 = 0.f, cs2 = 0.f;
#pragma unroll
    for (int k = 0; k < KC; ++k) {
      nl2 += scal[2 + k] * scal[2 + k];
      cs2 += scal[18 + k] * scal[18 + k];
    }
    const float fE = (float)NE;
    const float con = -(dotAG - sumLA) / (float)DH;
    const float trn = nl2 / (2.f * fE);
    const float spectral = -(tp - trn) / (2.f * fE);
    const float cluster = (sqrtf(cs2) / (float)N_NODES * 4.f - 1.f);
    out[0] = spectral + cluster + 0.5f * con;
  }
}

extern "C" void kernel_launch(void* const* d_in, const int* in_sizes, int n_in,
                              void* d_out, int out_size, void* d_ws, size_t ws_size,
                              hipStream_t stream) {
  const float* features = (const float*)d_in[0];
  const float* augf     = (const float*)d_in[1];
  const int*   grow     = (const int*)d_in[2];
  const int*   gcol     = (const int*)d_in[3];
  const float* gvals    = (const float*)d_in[4];
  const float* gnv      = (const float*)d_in[5];
  const float* W1       = (const float*)d_in[8];
  const float* b1       = (const float*)d_in[9];
  const float* Wt       = (const float*)d_in[10];
  const float* bt       = (const float*)d_in[11];

  char* ws = (char*)d_ws;
  size_t off = 0;
  auto alloc = [&](size_t bytes) -> void* {
    void* p = ws + off;
    off = (off + bytes + 255) & ~(size_t)255;
    return p;
  };
  unsigned short* Abf  = (unsigned short*)alloc((size_t)MPAD * KPAD * 2);
  unsigned short* Wbf  = (unsigned short*)alloc((size_t)DH * KPAD * 2);
  float* XW      = (float*)alloc((size_t)MPAD * DH * 4);
  float* gcn     = (float*)alloc((size_t)N_NODES * DH * 4);
  float* S       = (float*)alloc((size_t)N_NODES * KC * 4);
  int*   ecol    = (int*)alloc((size_t)NE * 4);
  float* eval    = (float*)alloc((size_t)NE * 4);
  int*   row_ptr = (int*)alloc((size_t)(N_NODES + 1) * 4);
  int*   cursor  = (int*)alloc((size_t)N_NODES * 4);
  int*   counts  = (int*)alloc((size_t)N_NODES * 4);
  float* pmax    = (float*)alloc((size_t)NB64 * DH * 4);
  float* psum    = (float*)alloc((size_t)NB64 * DH * 4);
  float* colmax  = (float*)alloc((size_t)DH * 4);
  float* augpart = (float*)alloc((size_t)64 * DH * 4);
  float* scal    = (float*)alloc(64 * 4);
  if (off > ws_size) return;  // workspace too small: fail loudly (wrong output), no OOB

  hipMemsetAsync(counts, 0, (size_t)N_NODES * 4, stream);
  hipMemsetAsync(augpart, 0, (size_t)64 * DH * 4, stream);
  hipMemsetAsync(scal, 0, 64 * 4, stream);

  // conversions
  k_cvt_pad<<<2048, 256, 0, stream>>>(features, Abf, N_NODES, N_FEAT, MPAD, KPAD);
  k_cvt_pad<<<256, 256, 0, stream>>>(W1, Wbf, DH, N_FEAT, DH, KPAD);

  // CSR build
  k_count<<<(NE + 255) / 256, 256, 0, stream>>>(grow, counts);
  k_scan<<<1, 1024, 0, stream>>>(counts, row_ptr, cursor);
  k_scatter<<<(NE + 255) / 256, 256, 0, stream>>>(grow, gcol, gnv, cursor, ecol, eval);

  // gcn pass
  dim3 gg(MPAD / 128, DH / 128);
  k_gemm_bt<<<gg, 256, 0, stream>>>(Abf, Wbf, XW);
  k_spmm_gcn<<<N_NODES / 4, 256, 0, stream>>>(row_ptr, ecol, eval, XW, b1, gcn);

  // assignments + graph stats
  k_assign<<<1024, 256, 0, stream>>>(gcn, Wt, bt, S);
  k_cs<<<64, 256, 0, stream>>>(S, scal + 18);
  k_edge<<<256, 256, 0, stream>>>(grow, gcol, gvals, S, scal + 2, scal + 1);

  // column logsumexp stats of gcn_out
  k_colmax_part<<<NB64, 256, 0, stream>>>(gcn, pmax);
  k_colmax_fin<<<1, 256, 0, stream>>>(pmax, colmax);
  k_colexp_part<<<NB64, 256, 0, stream>>>(gcn, colmax, psum);

  // aug pass (fused epilogue -> augpart, dotAG)
  k_cvt_pad<<<2048, 256, 0, stream>>>(augf, Abf, N_NODES, N_FEAT, MPAD, KPAD);
  k_gemm_bt<<<gg, 256, 0, stream>>>(Abf, Wbf, XW);
  k_spmm_aug<<<N_NODES / 4, 256, 0, stream>>>(row_ptr, ecol, eval, XW, b1, gcn,
                                              augpart, scal + 0);

  // final scalar
  k_final<<<1, 256, 0, stream>>>(psum, colmax, augpart, scal, (float*)d_out);
}

// Round 2
// 731.615 us; speedup vs baseline: 1.3308x; 1.3308x over previous
//
#include <hip/hip_runtime.h>
#include <math.h>

// Problem constants (fixed by reference)
#define N_NODES 50000
#define N_FEAT  500
#define DH      256
#define KC      16
#define NE      800000
#define KPAD    512     // N_FEAT padded to MFMA K multiple
#define MPAD    50048   // 391 * 128 (GEMM M tiles)

typedef __attribute__((ext_vector_type(8))) short short8;
typedef __attribute__((ext_vector_type(4))) float f32x4;

__device__ __forceinline__ unsigned short f2bf(float f) {
  unsigned u = __float_as_uint(f);
  u += 0x7FFFu + ((u >> 16) & 1u);   // RNE
  return (unsigned short)(u >> 16);
}

__device__ __forceinline__ float bf2f(unsigned short u) {
  return __uint_as_float((unsigned)u << 16);
}

__device__ __forceinline__ float selu_f(float x) {
  return 1.0507009873554805f * (x > 0.f ? x : 1.6732632423543772f * expm1f(x));
}

__device__ __forceinline__ void gload16(const void* g, void* l) {
  __builtin_amdgcn_global_load_lds(
      (const __attribute__((address_space(1))) unsigned int*)g,
      (__attribute__((address_space(3))) unsigned int*)l, 16, 0, 0);
}

// ---- f32 -> bf16 with zero padding: in [rin][cin] -> out [rout][cout] ----
__global__ void k_cvt_pad(const float* __restrict__ in, unsigned short* __restrict__ out,
                          int rin, int cin, int rout, int cout) {
  const int cquads = cout >> 2;
  const long total = (long)rout * cquads;
  for (long idx = (long)blockIdx.x * blockDim.x + threadIdx.x; idx < total;
       idx += (long)gridDim.x * blockDim.x) {
    const int row = (int)(idx / cquads);
    const int c4  = (int)(idx - (long)row * cquads) * 4;
    float x = 0.f, y = 0.f, z = 0.f, w = 0.f;
    if (row < rin && c4 < cin) {   // cin % 4 == 0, so c4+3 < cin too
      const float4 v = *(const float4*)(in + (size_t)row * cin + c4);
      x = v.x; y = v.y; z = v.z; w = v.w;
    }
    ushort4 o; o.x = f2bf(x); o.y = f2bf(y); o.z = f2bf(z); o.w = f2bf(w);
    *(ushort4*)(out + (size_t)row * cout + c4) = o;
  }
}

// ---- bf16 GEMM: C[m][n] = sum_k A[m][k]*B[n][k]; A [MPAD][KPAD], B [DH][KPAD]
//      C written as bf16 [MPAD][DH] ----
__global__ __launch_bounds__(256, 2) void k_gemm_bt(
    const unsigned short* __restrict__ A, const unsigned short* __restrict__ B,
    unsigned short* __restrict__ C) {
  __shared__ short As[128 * 64];
  __shared__ short Bs[128 * 64];
  const int t = threadIdx.x;
  const int lane = t & 63, wave = t >> 6;
  const int wr = (wave >> 1) * 64, wc = (wave & 1) * 64;
  const int bm = blockIdx.x * 128, bn = blockIdx.y * 128;
  const int lr = lane & 15, lk = (lane >> 4) * 8;
  f32x4 acc[4][4] = {};
  for (int kb = 0; kb < KPAD; kb += 64) {
#pragma unroll
    for (int i = 0; i < 4; ++i) {
      const int chunk = i * 256 + t;
      const int r = chunk >> 3, c8 = (chunk & 7) << 3;
      gload16(A + (size_t)(bm + r) * KPAD + kb + c8, (void*)(As + (size_t)chunk * 8));
      gload16(B + (size_t)(bn + r) * KPAD + kb + c8, (void*)(Bs + (size_t)chunk * 8));
    }
    __syncthreads();
#pragma unroll
    for (int kk = 0; kk < 64; kk += 32) {
      short8 af[4], bfr[4];
#pragma unroll
      for (int m = 0; m < 4; ++m)
        af[m] = *(const short8*)(As + (wr + m * 16 + lr) * 64 + kk + lk);
#pragma unroll
      for (int n = 0; n < 4; ++n)
        bfr[n] = *(const short8*)(Bs + (wc + n * 16 + lr) * 64 + kk + lk);
#pragma unroll
      for (int m = 0; m < 4; ++m)
#pragma unroll
        for (int n = 0; n < 4; ++n)
          acc[m][n] = __builtin_amdgcn_mfma_f32_16x16x32_bf16(af[m], bfr[n], acc[m][n], 0, 0, 0);
    }
    __syncthreads();
  }
  const int crow = (lane >> 4) * 4, ccol = lane & 15;
#pragma unroll
  for (int m = 0; m < 4; ++m)
#pragma unroll
    for (int n = 0; n < 4; ++n)
#pragma unroll
      for (int r = 0; r < 4; ++r)
        C[(size_t)(bm + wr + m * 16 + crow + r) * DH + (bn + wc + n * 16 + ccol)] =
            f2bf(acc[m][n][r]);
}

// ---- CSR build ----
__global__ void k_count(const int* __restrict__ row, int* __restrict__ counts) {
  const int e = blockIdx.x * blockDim.x + threadIdx.x;
  if (e < NE) atomicAdd(&counts[row[e]], 1);
}

__global__ __launch_bounds__(1024) void k_scan(const int* __restrict__ counts,
                                               int* __restrict__ row_ptr, int* __restrict__ cursor) {
  __shared__ int part[1024];
  const int t = threadIdx.x;
  const int per = (N_NODES + 1023) / 1024;
  const int base = t * per;
  int s = 0;
  for (int i = 0; i < per; ++i) { const int j = base + i; if (j < N_NODES) s += counts[j]; }
  part[t] = s;
  __syncthreads();
  for (int off = 1; off < 1024; off <<= 1) {
    const int v = (t >= off) ? part[t - off] : 0;
    __syncthreads();
    part[t] += v;
    __syncthreads();
  }
  int run = (t == 0) ? 0 : part[t - 1];
  for (int i = 0; i < per; ++i) {
    const int j = base + i;
    if (j < N_NODES) { row_ptr[j] = run; cursor[j] = run; run += counts[j]; }
  }
  if (t == 1023) row_ptr[N_NODES] = part[1023];
}

__global__ void k_scatter(const int* __restrict__ row, const int* __restrict__ col,
                          const float* __restrict__ gnv, int* __restrict__ cursor,
                          int* __restrict__ ecol, float* __restrict__ eval) {
  const int e = blockIdx.x * blockDim.x + threadIdx.x;
  if (e < NE) {
    const int p = atomicAdd(&cursor[row[e]], 1);
    ecol[p] = col[e];
    eval[p] = gnv[e];
  }
}

// ---- gather core: acc += v * bf16row(c), lane covers 4 cols ----
#define GATHER_BODY(XWp)                                                        \
  float ax = 0.f, ay = 0.f, az = 0.f, aw = 0.f;                                 \
  {                                                                             \
    int p = s;                                                                  \
    for (; p + 3 < e; p += 4) {                                                 \
      const int cA = ecol[p], cB = ecol[p + 1], cC = ecol[p + 2], cD = ecol[p + 3]; \
      const float vA = eval[p], vB = eval[p + 1], vC = eval[p + 2], vD = eval[p + 3]; \
      const ushort4 xA = *(const ushort4*)(XWp + (size_t)cA * DH + c0);         \
      const ushort4 xB = *(const ushort4*)(XWp + (size_t)cB * DH + c0);         \
      const ushort4 xC = *(const ushort4*)(XWp + (size_t)cC * DH + c0);         \
      const ushort4 xD = *(const ushort4*)(XWp + (size_t)cD * DH + c0);         \
      ax += vA * bf2f(xA.x); ay += vA * bf2f(xA.y); az += vA * bf2f(xA.z); aw += vA * bf2f(xA.w); \
      ax += vB * bf2f(xB.x); ay += vB * bf2f(xB.y); az += vB * bf2f(xB.z); aw += vB * bf2f(xB.w); \
      ax += vC * bf2f(xC.x); ay += vC * bf2f(xC.y); az += vC * bf2f(xC.z); aw += vC * bf2f(xC.w); \
      ax += vD * bf2f(xD.x); ay += vD * bf2f(xD.y); az += vD * bf2f(xD.z); aw += vD * bf2f(xD.w); \
    }                                                                           \
    for (; p < e; ++p) {                                                        \
      const int c = ecol[p];                                                    \
      const float v = eval[p];                                                  \
      const ushort4 x = *(const ushort4*)(XWp + (size_t)c * DH + c0);           \
      ax += v * bf2f(x.x); ay += v * bf2f(x.y); az += v * bf2f(x.z); aw += v * bf2f(x.w); \
    }                                                                           \
  }

// ---- SpMM + selu (gcn pass), fused: gcn bf16 out, assignments softmax,
//      per-column exp-sum partials (log_softmax denominator, no-max form) ----
__global__ __launch_bounds__(256) void k_spmm_gcn(
    const int* __restrict__ row_ptr, const int* __restrict__ ecol, const float* __restrict__ eval,
    const unsigned short* __restrict__ XW, const float* __restrict__ b1,
    const float* __restrict__ Wt, const float* __restrict__ bt,
    unsigned short* __restrict__ gcn, float* __restrict__ S, float* __restrict__ exppart) {
  __shared__ float Wl[KC * DH];
  __shared__ float btl[KC];
  __shared__ float expacc[DH];
  for (int i = threadIdx.x; i < KC * DH; i += 256) Wl[i] = Wt[i];
  if (threadIdx.x < KC) btl[threadIdx.x] = bt[threadIdx.x];
  expacc[threadIdx.x] = 0.f;
  __syncthreads();
  const int wave = threadIdx.x >> 6, lane = threadIdx.x & 63;
  const int i = blockIdx.x * 4 + wave;
  const int c0 = lane * 4;
  const int s = row_ptr[i], e = row_ptr[i + 1];
  GATHER_BODY(XW)
  const float4 b = *(const float4*)(b1 + c0);
  const float o0 = selu_f(ax + b.x), o1 = selu_f(ay + b.y);
  const float o2 = selu_f(az + b.z), o3 = selu_f(aw + b.w);
  ushort4 go; go.x = f2bf(o0); go.y = f2bf(o1); go.z = f2bf(o2); go.w = f2bf(o3);
  *(ushort4*)(gcn + (size_t)i * DH + c0) = go;
  // exp colsum partials (no-max logsumexp; |o| bounded ~21, exp fits f32)
  atomicAdd(&expacc[c0 + 0], expf(o0));
  atomicAdd(&expacc[c0 + 1], expf(o1));
  atomicAdd(&expacc[c0 + 2], expf(o2));
  atomicAdd(&expacc[c0 + 3], expf(o3));
  // assignments = softmax(o @ Wt^T + bt)
  float lg[KC];
#pragma unroll
  for (int k = 0; k < KC; ++k) {
    const float4 w = *(const float4*)(Wl + k * DH + c0);
    lg[k] = o0 * w.x + o1 * w.y + o2 * w.z + o3 * w.w;
  }
#pragma unroll
  for (int off = 32; off; off >>= 1)
#pragma unroll
    for (int k = 0; k < KC; ++k) lg[k] += __shfl_xor(lg[k], off);
  float mx = -3.4e38f;
#pragma unroll
  for (int k = 0; k < KC; ++k) { lg[k] += btl[k]; mx = fmaxf(mx, lg[k]); }
  float se = 0.f;
#pragma unroll
  for (int k = 0; k < KC; ++k) { lg[k] = expf(lg[k] - mx); se += lg[k]; }
  const float inv = 1.f / se;
  float myv = 0.f;
#pragma unroll
  for (int k = 0; k < KC; ++k) if (lane == k) myv = lg[k];
  if (lane < KC) S[(size_t)i * KC + lane] = myv * inv;
  __syncthreads();
  atomicAdd(&exppart[(size_t)(blockIdx.x & 63) * DH + threadIdx.x], expacc[threadIdx.x]);
}

// ---- SpMM + selu (aug pass), fused epilogue: colSumAug partials + dot(aug,gcn) ----
__global__ __launch_bounds__(256) void k_spmm_aug(
    const int* __restrict__ row_ptr, const int* __restrict__ ecol, const float* __restrict__ eval,
    const unsigned short* __restrict__ XW, const float* __restrict__ b1,
    const unsigned short* __restrict__ gcn,
    float* __restrict__ augpart, float* __restrict__ dotAG) {
  __shared__ float colacc[DH];
  __shared__ float dacc;
  colacc[threadIdx.x] = 0.f;
  if (threadIdx.x == 0) dacc = 0.f;
  __syncthreads();
  const int wave = threadIdx.x >> 6, lane = threadIdx.x & 63;
  const int i = blockIdx.x * 4 + wave;
  const int c0 = lane * 4;
  const int s = row_ptr[i], e = row_ptr[i + 1];
  GATHER_BODY(XW)
  const float4 b = *(const float4*)(b1 + c0);
  const float sx = selu_f(ax + b.x), sy = selu_f(ay + b.y);
  const float sz = selu_f(az + b.z), sw = selu_f(aw + b.w);
  const ushort4 g = *(const ushort4*)(gcn + (size_t)i * DH + c0);
  float d = sx * bf2f(g.x) + sy * bf2f(g.y) + sz * bf2f(g.z) + sw * bf2f(g.w);
#pragma unroll
  for (int off = 32; off; off >>= 1) d += __shfl_xor(d, off);
  if (lane == 0) atomicAdd(&dacc, d);
  atomicAdd(&colacc[c0 + 0], sx);
  atomicAdd(&colacc[c0 + 1], sy);
  atomicAdd(&colacc[c0 + 2], sz);
  atomicAdd(&colacc[c0 + 3], sw);
  __syncthreads();
  atomicAdd(&augpart[(size_t)(blockIdx.x & 63) * DH + threadIdx.x], colacc[threadIdx.x]);
  if (threadIdx.x == 0) atomicAdd(dotAG, dacc);
}

// ---- cluster sizes: cs[k] = sum_n S[n,k] ----
__global__ void k_cs(const float* __restrict__ S, float* __restrict__ cs) {
  const int t = threadIdx.x;
  float local = 0.f;
  for (long idx = (long)blockIdx.x * 256 + t; idx < (long)N_NODES * KC; idx += (long)gridDim.x * 256)
    local += S[idx];
  __shared__ float red[256];
  red[t] = local;
  __syncthreads();
  if (t < KC) {
    float s = 0.f;
#pragma unroll
    for (int j = 0; j < 16; ++j) s += red[t + KC * j];
    atomicAdd(&cs[t], s);
  }
}

// ---- edge stats: tp = sum_e v*dot16(S[row],S[col]); nl[k] = sum_e v*S[col,k] ----
__global__ __launch_bounds__(256) void k_edge(const int* __restrict__ grow, const int* __restrict__ gcol,
                                              const float* __restrict__ gvals, const float* __restrict__ S,
                                              float* __restrict__ nl, float* __restrict__ tp) {
  float ltp = 0.f;
  float lnl[KC];
#pragma unroll
  for (int k = 0; k < KC; ++k) lnl[k] = 0.f;
  for (long e = (long)blockIdx.x * 256 + threadIdx.x; e < NE; e += (long)gridDim.x * 256) {
    const int r = grow[e], c = gcol[e];
    const float v = gvals[e];
    const float4* sr = (const float4*)(S + (size_t)r * KC);
    const float4* sc = (const float4*)(S + (size_t)c * KC);
    const float4 a0 = sr[0], a1 = sr[1], a2 = sr[2], a3 = sr[3];
    const float4 b0 = sc[0], b1v = sc[1], b2 = sc[2], b3 = sc[3];
    const float dot = a0.x * b0.x + a0.y * b0.y + a0.z * b0.z + a0.w * b0.w
                    + a1.x * b1v.x + a1.y * b1v.y + a1.z * b1v.z + a1.w * b1v.w
                    + a2.x * b2.x + a2.y * b2.y + a2.z * b2.z + a2.w * b2.w
                    + a3.x * b3.x + a3.y * b3.y + a3.z * b3.z + a3.w * b3.w;
    ltp += v * dot;
    lnl[0] += v * b0.x;  lnl[1] += v * b0.y;  lnl[2] += v * b0.z;  lnl[3] += v * b0.w;
    lnl[4] += v * b1v.x; lnl[5] += v * b1v.y; lnl[6] += v * b1v.z; lnl[7] += v * b1v.w;
    lnl[8] += v * b2.x;  lnl[9] += v * b2.y;  lnl[10] += v * b2.z; lnl[11] += v * b2.w;
    lnl[12] += v * b3.x; lnl[13] += v * b3.y; lnl[14] += v * b3.z; lnl[15] += v * b3.w;
  }
#pragma unroll
  for (int off = 32; off; off >>= 1) {
    ltp += __shfl_xor(ltp, off);
#pragma unroll
    for (int k = 0; k < KC; ++k) lnl[k] += __shfl_xor(lnl[k], off);
  }
  __shared__ float wred[4][KC + 1];
  const int wave = threadIdx.x >> 6, lane = threadIdx.x & 63;
  if (lane == 0) {
    wred[wave][0] = ltp;
#pragma unroll
    for (int k = 0; k < KC; ++k) wred[wave][1 + k] = lnl[k];
  }
  __syncthreads();
  if (threadIdx.x < KC + 1) {
    const float s = wred[0][threadIdx.x] + wred[1][threadIdx.x] + wred[2][threadIdx.x] + wred[3][threadIdx.x];
    if (threadIdx.x == 0) atomicAdd(tp, s);
    else atomicAdd(&nl[threadIdx.x - 1], s);
  }
}

// ---- final scalar assembly ----
// scal layout: [0]=dotAG, [1]=tp, [2..17]=nl, [18..33]=cs
__global__ void k_final(const float* __restrict__ exppart, const float* __restrict__ augpart,
                        const float* __restrict__ scal, float* __restrict__ out) {
  const int d = threadIdx.x;
  float es = 0.f, sa = 0.f;
  for (int b = 0; b < 64; ++b) {
    es += exppart[(size_t)b * DH + d];
    sa += augpart[(size_t)b * DH + d];
  }
  const float L = logf(es);
  __shared__ float red[DH];
  red[d] = L * sa;
  __syncthreads();
  for (int off = 128; off; off >>= 1) {
    if (d < off) red[d] += red[d + off];
    __syncthreads();
  }
  if (d == 0) {
    const float sumLA = red[0];
    const float dotAG = scal[0];
    const float tp = scal[1];
    float nl2 = 0.f, cs2 = 0.f;
#pragma unroll
    for (int k = 0; k < KC; ++k) {
      nl2 += scal[2 + k] * scal[2 + k];
      cs2 += scal[18 + k] * scal[18 + k];
    }
    const float fE = (float)NE;
    const float con = -(dotAG - sumLA) / (float)DH;
    const float trn = nl2 / (2.f * fE);
    const float spectral = -(tp - trn) / (2.f * fE);
    const float cluster = (sqrtf(cs2) / (float)N_NODES * 4.f - 1.f);
    out[0] = spectral + cluster + 0.5f * con;
  }
}

extern "C" void kernel_launch(void* const* d_in, const int* in_sizes, int n_in,
                              void* d_out, int out_size, void* d_ws, size_t ws_size,
                              hipStream_t stream) {
  const float* features = (const float*)d_in[0];
  const float* augf     = (const float*)d_in[1];
  const int*   grow     = (const int*)d_in[2];
  const int*   gcol     = (const int*)d_in[3];
  const float* gvals    = (const float*)d_in[4];
  const float* gnv      = (const float*)d_in[5];
  const float* W1       = (const float*)d_in[8];
  const float* b1       = (const float*)d_in[9];
  const float* Wt       = (const float*)d_in[10];
  const float* bt       = (const float*)d_in[11];

  char* ws = (char*)d_ws;
  size_t off = 0;
  auto alloc = [&](size_t bytes) -> void* {
    void* p = ws + off;
    off = (off + bytes + 255) & ~(size_t)255;
    return p;
  };
  unsigned short* Abf  = (unsigned short*)alloc((size_t)MPAD * KPAD * 2);
  unsigned short* Wbf  = (unsigned short*)alloc((size_t)DH * KPAD * 2);
  unsigned short* XW   = (unsigned short*)alloc((size_t)MPAD * DH * 2);
  unsigned short* gcn  = (unsigned short*)alloc((size_t)N_NODES * DH * 2);
  float* S       = (float*)alloc((size_t)N_NODES * KC * 4);
  int*   ecol    = (int*)alloc((size_t)NE * 4);
  float* eval    = (float*)alloc((size_t)NE * 4);
  int*   row_ptr = (int*)alloc((size_t)(N_NODES + 1) * 4);
  int*   cursor  = (int*)alloc((size_t)N_NODES * 4);
  int*   counts  = (int*)alloc((size_t)N_NODES * 4);
  float* exppart = (float*)alloc((size_t)64 * DH * 4);
  float* augpart = (float*)alloc((size_t)64 * DH * 4);
  float* scal    = (float*)alloc(64 * 4);
  if (off > ws_size) return;  // workspace too small: fail loudly (wrong output), no OOB

  hipMemsetAsync(counts, 0, (size_t)N_NODES * 4, stream);
  hipMemsetAsync(exppart, 0, (size_t)64 * DH * 4, stream);
  hipMemsetAsync(augpart, 0, (size_t)64 * DH * 4, stream);
  hipMemsetAsync(scal, 0, 64 * 4, stream);

  // conversions
  k_cvt_pad<<<2048, 256, 0, stream>>>(features, Abf, N_NODES, N_FEAT, MPAD, KPAD);
  k_cvt_pad<<<256, 256, 0, stream>>>(W1, Wbf, DH, N_FEAT, DH, KPAD);

  // CSR build
  k_count<<<(NE + 255) / 256, 256, 0, stream>>>(grow, counts);
  k_scan<<<1, 1024, 0, stream>>>(counts, row_ptr, cursor);
  k_scatter<<<(NE + 255) / 256, 256, 0, stream>>>(grow, gcol, gnv, cursor, ecol, eval);

  // gcn pass (GEMM -> bf16 XW; SpMM fused with assignments + exp colsums)
  dim3 gg(MPAD / 128, DH / 128);
  k_gemm_bt<<<gg, 256, 0, stream>>>(Abf, Wbf, XW);
  k_spmm_gcn<<<N_NODES / 4, 256, 0, stream>>>(row_ptr, ecol, eval, XW, b1, Wt, bt,
                                              gcn, S, exppart);

  // graph stats on assignments
  k_cs<<<64, 256, 0, stream>>>(S, scal + 18);
  k_edge<<<256, 256, 0, stream>>>(grow, gcol, gvals, S, scal + 2, scal + 1);

  // aug pass (fused epilogue -> augpart, dotAG)
  k_cvt_pad<<<2048, 256, 0, stream>>>(augf, Abf, N_NODES, N_FEAT, MPAD, KPAD);
  k_gemm_bt<<<gg, 256, 0, stream>>>(Abf, Wbf, XW);
  k_spmm_aug<<<N_NODES / 4, 256, 0, stream>>>(row_ptr, ecol, eval, XW, b1, gcn,
                                              augpart, scal + 0);

  // final scalar
  k_final<<<1, 256, 0, stream>>>(exppart, augpart, scal, (float*)d_out);
}

// Round 3
// 618.818 us; speedup vs baseline: 1.5734x; 1.1823x over previous
//
#include <hip/hip_runtime.h>
#include <math.h>

// Problem constants (fixed by reference)
#define N_NODES 50000
#define N_FEAT  500
#define DH      256
#define KC      16
#define NE      800000
#define KPAD    512     // N_FEAT padded to MFMA K multiple
#define MPAD    50048   // 391 * 128 (GEMM M tiles)

typedef __attribute__((ext_vector_type(8))) short short8;
typedef __attribute__((ext_vector_type(4))) float f32x4;

__device__ __forceinline__ unsigned short f2bf(float f) {
  unsigned u = __float_as_uint(f);
  u += 0x7FFFu + ((u >> 16) & 1u);   // RNE
  return (unsigned short)(u >> 16);
}

__device__ __forceinline__ float bf2f(unsigned short u) {
  return __uint_as_float((unsigned)u << 16);
}

__device__ __forceinline__ float selu_f(float x) {
  return 1.0507009873554805f * (x > 0.f ? x : 1.6732632423543772f * expm1f(x));
}

__device__ __forceinline__ void gload16(const void* g, void* l) {
  __builtin_amdgcn_global_load_lds(
      (const __attribute__((address_space(1))) unsigned int*)g,
      (__attribute__((address_space(3))) unsigned int*)l, 16, 0, 0);
}

// ---- f32 -> bf16 with zero padding: in [rin][cin] -> out [rout][cout] ----
__global__ void k_cvt_pad(const float* __restrict__ in, unsigned short* __restrict__ out,
                          int rin, int cin, int rout, int cout) {
  const int cquads = cout >> 2;
  const long total = (long)rout * cquads;
  for (long idx = (long)blockIdx.x * blockDim.x + threadIdx.x; idx < total;
       idx += (long)gridDim.x * blockDim.x) {
    const int row = (int)(idx / cquads);
    const int c4  = (int)(idx - (long)row * cquads) * 4;
    float x = 0.f, y = 0.f, z = 0.f, w = 0.f;
    if (row < rin && c4 < cin) {   // cin % 4 == 0, so c4+3 < cin too
      const float4 v = *(const float4*)(in + (size_t)row * cin + c4);
      x = v.x; y = v.y; z = v.z; w = v.w;
    }
    ushort4 o; o.x = f2bf(x); o.y = f2bf(y); o.z = f2bf(z); o.w = f2bf(w);
    *(ushort4*)(out + (size_t)row * cout + c4) = o;
  }
}

// ---- bf16 GEMM: C[m][n] = sum_k A[m][k]*B[n][k]; A [M2][KPAD], B [DH][KPAD]
//      C written as bf16 [M2][DH]; M2 = 2*MPAD (features stacked with aug) ----
__global__ __launch_bounds__(256, 2) void k_gemm_bt(
    const unsigned short* __restrict__ A, const unsigned short* __restrict__ B,
    unsigned short* __restrict__ C) {
  __shared__ short As[128 * 64];
  __shared__ short Bs[128 * 64];
  const int t = threadIdx.x;
  const int lane = t & 63, wave = t >> 6;
  const int wr = (wave >> 1) * 64, wc = (wave & 1) * 64;
  const int bm = blockIdx.x * 128, bn = blockIdx.y * 128;
  const int lr = lane & 15, lk = (lane >> 4) * 8;
  f32x4 acc[4][4] = {};
  for (int kb = 0; kb < KPAD; kb += 64) {
#pragma unroll
    for (int i = 0; i < 4; ++i) {
      const int chunk = i * 256 + t;
      const int r = chunk >> 3, c8 = (chunk & 7) << 3;
      gload16(A + (size_t)(bm + r) * KPAD + kb + c8, (void*)(As + (size_t)chunk * 8));
      gload16(B + (size_t)(bn + r) * KPAD + kb + c8, (void*)(Bs + (size_t)chunk * 8));
    }
    __syncthreads();
#pragma unroll
    for (int kk = 0; kk < 64; kk += 32) {
      short8 af[4], bfr[4];
#pragma unroll
      for (int m = 0; m < 4; ++m)
        af[m] = *(const short8*)(As + (wr + m * 16 + lr) * 64 + kk + lk);
#pragma unroll
      for (int n = 0; n < 4; ++n)
        bfr[n] = *(const short8*)(Bs + (wc + n * 16 + lr) * 64 + kk + lk);
#pragma unroll
      for (int m = 0; m < 4; ++m)
#pragma unroll
        for (int n = 0; n < 4; ++n)
          acc[m][n] = __builtin_amdgcn_mfma_f32_16x16x32_bf16(af[m], bfr[n], acc[m][n], 0, 0, 0);
    }
    __syncthreads();
  }
  const int crow = (lane >> 4) * 4, ccol = lane & 15;
#pragma unroll
  for (int m = 0; m < 4; ++m)
#pragma unroll
    for (int n = 0; n < 4; ++n)
#pragma unroll
      for (int r = 0; r < 4; ++r)
        C[(size_t)(bm + wr + m * 16 + crow + r) * DH + (bn + wc + n * 16 + ccol)] =
            f2bf(acc[m][n][r]);
}

// ---- CSR build ----
__global__ void k_count(const int* __restrict__ row, int* __restrict__ counts) {
  const int e = blockIdx.x * blockDim.x + threadIdx.x;
  if (e < NE) atomicAdd(&counts[row[e]], 1);
}

__global__ __launch_bounds__(1024) void k_scan(const int* __restrict__ counts,
                                               int* __restrict__ row_ptr, int* __restrict__ cursor) {
  __shared__ int part[1024];
  const int t = threadIdx.x;
  const int per = (N_NODES + 1023) / 1024;
  const int base = t * per;
  int s = 0;
  for (int i = 0; i < per; ++i) { const int j = base + i; if (j < N_NODES) s += counts[j]; }
  part[t] = s;
  __syncthreads();
  for (int off = 1; off < 1024; off <<= 1) {
    const int v = (t >= off) ? part[t - off] : 0;
    __syncthreads();
    part[t] += v;
    __syncthreads();
  }
  int run = (t == 0) ? 0 : part[t - 1];
  for (int i = 0; i < per; ++i) {
    const int j = base + i;
    if (j < N_NODES) { row_ptr[j] = run; cursor[j] = run; run += counts[j]; }
  }
  if (t == 1023) row_ptr[N_NODES] = part[1023];
}

__global__ void k_scatter(const int* __restrict__ row, const int* __restrict__ col,
                          const float* __restrict__ gnv, int* __restrict__ cursor,
                          int* __restrict__ ecol, float* __restrict__ eval) {
  const int e = blockIdx.x * blockDim.x + threadIdx.x;
  if (e < NE) {
    const int p = atomicAdd(&cursor[row[e]], 1);
    ecol[p] = col[e];
    eval[p] = gnv[e];
  }
}

// ---- Combined SpMM (both feature and aug matrices) + full fused epilogue.
//      One wave per row; half-wave (32 lanes) covers a full 512B bf16 row,
//      each lane holds 8 columns. Per iteration: 8 edges, 8 independent 1KB
//      gathers in flight. Epilogue (all in-register, no gcn buffer):
//        of = selu(A@XWf + b1); oa = selu(A@XWa + b1)
//        S[i]      = softmax(of @ Wt^T + bt)
//        exppart  += exp(of) per column      (log_softmax denominator)
//        augpart  += oa per column
//        dotAG    += dot(oa, of)
__global__ __launch_bounds__(256, 4) void k_spmm_fused(
    const int* __restrict__ row_ptr, const int* __restrict__ ecol, const float* __restrict__ eval,
    const unsigned short* __restrict__ XWf, const unsigned short* __restrict__ XWa,
    const float* __restrict__ b1, const float* __restrict__ Wt, const float* __restrict__ bt,
    float* __restrict__ S, float* __restrict__ exppart, float* __restrict__ augpart,
    float* __restrict__ dotAG) {
  __shared__ float Wl[KC * DH];
  __shared__ float btl[KC];
  __shared__ float expacc[DH];
  __shared__ float augacc[DH];
  __shared__ float dacc;
  for (int i4 = threadIdx.x; i4 < KC * DH / 4; i4 += 256)
    ((float4*)Wl)[i4] = ((const float4*)Wt)[i4];
  if (threadIdx.x < KC) btl[threadIdx.x] = bt[threadIdx.x];
  expacc[threadIdx.x] = 0.f;
  augacc[threadIdx.x] = 0.f;
  if (threadIdx.x == 0) dacc = 0.f;
  __syncthreads();

  const int wave = threadIdx.x >> 6, lane = threadIdx.x & 63;
  const int half = lane >> 5;          // 0 or 1: which edge of the pair
  const int c0   = (lane & 31) * 8;    // 8 columns per lane
  const int i = blockIdx.x * 4 + wave;
  const int s = row_ptr[i], e = row_ptr[i + 1];

  float accf[8] = {0.f, 0.f, 0.f, 0.f, 0.f, 0.f, 0.f, 0.f};
  float acca[8] = {0.f, 0.f, 0.f, 0.f, 0.f, 0.f, 0.f, 0.f};

  for (int pb = s; pb < e; pb += 8) {
    int ci[4]; float vi[4];
#pragma unroll
    for (int j = 0; j < 4; ++j) {
      const int q = pb + 2 * j + half;
      const bool act = q < e;
      const int qi = act ? q : 0;
      ci[j] = ecol[qi];
      vi[j] = act ? eval[qi] : 0.f;
    }
    short8 xf[4], xa[4];
#pragma unroll
    for (int j = 0; j < 4; ++j) {
      xf[j] = *(const short8*)(XWf + (size_t)ci[j] * DH + c0);
      xa[j] = *(const short8*)(XWa + (size_t)ci[j] * DH + c0);
    }
#pragma unroll
    for (int j = 0; j < 4; ++j)
#pragma unroll
      for (int u = 0; u < 8; ++u) {
        accf[u] += vi[j] * bf2f((unsigned short)xf[j][u]);
        acca[u] += vi[j] * bf2f((unsigned short)xa[j][u]);
      }
  }
  // fold the two halves (both end up with the full row sums)
#pragma unroll
  for (int u = 0; u < 8; ++u) {
    accf[u] += __shfl_xor(accf[u], 32);
    acca[u] += __shfl_xor(acca[u], 32);
  }

  // bias + selu
  const float4 blo = *(const float4*)(b1 + c0);
  const float4 bhi = *(const float4*)(b1 + c0 + 4);
  float of[8], oa[8];
  of[0] = selu_f(accf[0] + blo.x); of[1] = selu_f(accf[1] + blo.y);
  of[2] = selu_f(accf[2] + blo.z); of[3] = selu_f(accf[3] + blo.w);
  of[4] = selu_f(accf[4] + bhi.x); of[5] = selu_f(accf[5] + bhi.y);
  of[6] = selu_f(accf[6] + bhi.z); of[7] = selu_f(accf[7] + bhi.w);
  oa[0] = selu_f(acca[0] + blo.x); oa[1] = selu_f(acca[1] + blo.y);
  oa[2] = selu_f(acca[2] + blo.z); oa[3] = selu_f(acca[3] + blo.w);
  oa[4] = selu_f(acca[4] + bhi.x); oa[5] = selu_f(acca[5] + bhi.y);
  oa[6] = selu_f(acca[6] + bhi.z); oa[7] = selu_f(acca[7] + bhi.w);

  // per-column partials (half 0 only; halves are duplicates after fold)
  if (half == 0) {
#pragma unroll
    for (int u = 0; u < 8; ++u) {
      atomicAdd(&expacc[c0 + u], expf(of[u]));
      atomicAdd(&augacc[c0 + u], oa[u]);
    }
  }

  // dot(oa, of) -> dacc
  float d = 0.f;
#pragma unroll
  for (int u = 0; u < 8; ++u) d += oa[u] * of[u];
#pragma unroll
  for (int off = 16; off; off >>= 1) d += __shfl_xor(d, off);
  if (lane == 0) atomicAdd(&dacc, d);

  // assignments = softmax(of @ Wt^T + bt)
  float lg[KC];
#pragma unroll
  for (int k = 0; k < KC; ++k) {
    const float4 wlo = *(const float4*)(Wl + k * DH + c0);
    const float4 whi = *(const float4*)(Wl + k * DH + c0 + 4);
    lg[k] = of[0] * wlo.x + of[1] * wlo.y + of[2] * wlo.z + of[3] * wlo.w
          + of[4] * whi.x + of[5] * whi.y + of[6] * whi.z + of[7] * whi.w;
  }
#pragma unroll
  for (int off = 16; off; off >>= 1)
#pragma unroll
    for (int k = 0; k < KC; ++k) lg[k] += __shfl_xor(lg[k], off);
  float mx = -3.4e38f;
#pragma unroll
  for (int k = 0; k < KC; ++k) { lg[k] += btl[k]; mx = fmaxf(mx, lg[k]); }
  float se = 0.f;
#pragma unroll
  for (int k = 0; k < KC; ++k) { lg[k] = expf(lg[k] - mx); se += lg[k]; }
  const float inv = 1.f / se;
  float myv = 0.f;
#pragma unroll
  for (int k = 0; k < KC; ++k) if (lane == k) myv = lg[k];
  if (lane < KC) S[(size_t)i * KC + lane] = myv * inv;

  __syncthreads();
  atomicAdd(&exppart[(size_t)(blockIdx.x & 63) * DH + threadIdx.x], expacc[threadIdx.x]);
  atomicAdd(&augpart[(size_t)(blockIdx.x & 63) * DH + threadIdx.x], augacc[threadIdx.x]);
  if (threadIdx.x == 0) atomicAdd(dotAG, dacc);
}

// ---- cluster sizes: cs[k] = sum_n S[n,k] ----
__global__ void k_cs(const float* __restrict__ S, float* __restrict__ cs) {
  const int t = threadIdx.x;
  float local = 0.f;
  for (long idx = (long)blockIdx.x * 256 + t; idx < (long)N_NODES * KC; idx += (long)gridDim.x * 256)
    local += S[idx];
  __shared__ float red[256];
  red[t] = local;
  __syncthreads();
  if (t < KC) {
    float s = 0.f;
#pragma unroll
    for (int j = 0; j < 16; ++j) s += red[t + KC * j];
    atomicAdd(&cs[t], s);
  }
}

// ---- edge stats: tp = sum_e v*dot16(S[row],S[col]); nl[k] = sum_e v*S[col,k] ----
__global__ __launch_bounds__(256) void k_edge(const int* __restrict__ grow, const int* __restrict__ gcol,
                                              const float* __restrict__ gvals, const float* __restrict__ S,
                                              float* __restrict__ nl, float* __restrict__ tp) {
  float ltp = 0.f;
  float lnl[KC];
#pragma unroll
  for (int k = 0; k < KC; ++k) lnl[k] = 0.f;
  for (long e = (long)blockIdx.x * 256 + threadIdx.x; e < NE; e += (long)gridDim.x * 256) {
    const int r = grow[e], c = gcol[e];
    const float v = gvals[e];
    const float4* sr = (const float4*)(S + (size_t)r * KC);
    const float4* sc = (const float4*)(S + (size_t)c * KC);
    const float4 a0 = sr[0], a1 = sr[1], a2 = sr[2], a3 = sr[3];
    const float4 b0 = sc[0], b1v = sc[1], b2 = sc[2], b3 = sc[3];
    const float dot = a0.x * b0.x + a0.y * b0.y + a0.z * b0.z + a0.w * b0.w
                    + a1.x * b1v.x + a1.y * b1v.y + a1.z * b1v.z + a1.w * b1v.w
                    + a2.x * b2.x + a2.y * b2.y + a2.z * b2.z + a2.w * b2.w
                    + a3.x * b3.x + a3.y * b3.y + a3.z * b3.z + a3.w * b3.w;
    ltp += v * dot;
    lnl[0] += v * b0.x;  lnl[1] += v * b0.y;  lnl[2] += v * b0.z;  lnl[3] += v * b0.w;
    lnl[4] += v * b1v.x; lnl[5] += v * b1v.y; lnl[6] += v * b1v.z; lnl[7] += v * b1v.w;
    lnl[8] += v * b2.x;  lnl[9] += v * b2.y;  lnl[10] += v * b2.z; lnl[11] += v * b2.w;
    lnl[12] += v * b3.x; lnl[13] += v * b3.y; lnl[14] += v * b3.z; lnl[15] += v * b3.w;
  }
#pragma unroll
  for (int off = 32; off; off >>= 1) {
    ltp += __shfl_xor(ltp, off);
#pragma unroll
    for (int k = 0; k < KC; ++k) lnl[k] += __shfl_xor(lnl[k], off);
  }
  __shared__ float wred[4][KC + 1];
  const int wave = threadIdx.x >> 6, lane = threadIdx.x & 63;
  if (lane == 0) {
    wred[wave][0] = ltp;
#pragma unroll
    for (int k = 0; k < KC; ++k) wred[wave][1 + k] = lnl[k];
  }
  __syncthreads();
  if (threadIdx.x < KC + 1) {
    const float s = wred[0][threadIdx.x] + wred[1][threadIdx.x] + wred[2][threadIdx.x] + wred[3][threadIdx.x];
    if (threadIdx.x == 0) atomicAdd(tp, s);
    else atomicAdd(&nl[threadIdx.x - 1], s);
  }
}

// ---- final scalar assembly ----
// scal layout: [0]=dotAG, [1]=tp, [2..17]=nl, [18..33]=cs
__global__ void k_final(const float* __restrict__ exppart, const float* __restrict__ augpart,
                        const float* __restrict__ scal, float* __restrict__ out) {
  const int d = threadIdx.x;
  float es = 0.f, sa = 0.f;
  for (int b = 0; b < 64; ++b) {
    es += exppart[(size_t)b * DH + d];
    sa += augpart[(size_t)b * DH + d];
  }
  const float L = logf(es);
  __shared__ float red[DH];
  red[d] = L * sa;
  __syncthreads();
  for (int off = 128; off; off >>= 1) {
    if (d < off) red[d] += red[d + off];
    __syncthreads();
  }
  if (d == 0) {
    const float sumLA = red[0];
    const float dotAG = scal[0];
    const float tp = scal[1];
    float nl2 = 0.f, cs2 = 0.f;
#pragma unroll
    for (int k = 0; k < KC; ++k) {
      nl2 += scal[2 + k] * scal[2 + k];
      cs2 += scal[18 + k] * scal[18 + k];
    }
    const float fE = (float)NE;
    const float con = -(dotAG - sumLA) / (float)DH;
    const float trn = nl2 / (2.f * fE);
    const float spectral = -(tp - trn) / (2.f * fE);
    const float cluster = (sqrtf(cs2) / (float)N_NODES * 4.f - 1.f);
    out[0] = spectral + cluster + 0.5f * con;
  }
}

extern "C" void kernel_launch(void* const* d_in, const int* in_sizes, int n_in,
                              void* d_out, int out_size, void* d_ws, size_t ws_size,
                              hipStream_t stream) {
  const float* features = (const float*)d_in[0];
  const float* augf     = (const float*)d_in[1];
  const int*   grow     = (const int*)d_in[2];
  const int*   gcol     = (const int*)d_in[3];
  const float* gvals    = (const float*)d_in[4];
  const float* gnv      = (const float*)d_in[5];
  const float* W1       = (const float*)d_in[8];
  const float* b1       = (const float*)d_in[9];
  const float* Wt       = (const float*)d_in[10];
  const float* bt       = (const float*)d_in[11];

  char* ws = (char*)d_ws;
  size_t off = 0;
  auto alloc = [&](size_t bytes) -> void* {
    void* p = ws + off;
    off = (off + bytes + 255) & ~(size_t)255;
    return p;
  };
  // Abf/XW stacked: [0..MPAD) = features, [MPAD..2*MPAD) = aug
  unsigned short* Abf  = (unsigned short*)alloc((size_t)2 * MPAD * KPAD * 2);
  unsigned short* Wbf  = (unsigned short*)alloc((size_t)DH * KPAD * 2);
  unsigned short* XW   = (unsigned short*)alloc((size_t)2 * MPAD * DH * 2);
  float* S       = (float*)alloc((size_t)N_NODES * KC * 4);
  int*   ecol    = (int*)alloc((size_t)NE * 4);
  float* eval    = (float*)alloc((size_t)NE * 4);
  int*   row_ptr = (int*)alloc((size_t)(N_NODES + 1) * 4);
  int*   cursor  = (int*)alloc((size_t)N_NODES * 4);
  int*   counts  = (int*)alloc((size_t)N_NODES * 4);
  float* exppart = (float*)alloc((size_t)64 * DH * 4);
  float* augpart = (float*)alloc((size_t)64 * DH * 4);
  float* scal    = (float*)alloc(64 * 4);
  if (off > ws_size) return;  // workspace too small: fail loudly (wrong output), no OOB

  hipMemsetAsync(counts, 0, (size_t)N_NODES * 4, stream);
  hipMemsetAsync(exppart, 0, (size_t)64 * DH * 4, stream);
  hipMemsetAsync(augpart, 0, (size_t)64 * DH * 4, stream);
  hipMemsetAsync(scal, 0, 64 * 4, stream);

  // conversions (both inputs into the stacked Abf)
  k_cvt_pad<<<2048, 256, 0, stream>>>(features, Abf, N_NODES, N_FEAT, MPAD, KPAD);
  k_cvt_pad<<<2048, 256, 0, stream>>>(augf, Abf + (size_t)MPAD * KPAD, N_NODES, N_FEAT, MPAD, KPAD);
  k_cvt_pad<<<256, 256, 0, stream>>>(W1, Wbf, DH, N_FEAT, DH, KPAD);

  // CSR build
  k_count<<<(NE + 255) / 256, 256, 0, stream>>>(grow, counts);
  k_scan<<<1, 1024, 0, stream>>>(counts, row_ptr, cursor);
  k_scatter<<<(NE + 255) / 256, 256, 0, stream>>>(grow, gcol, gnv, cursor, ecol, eval);

  // one GEMM covering both matrices (M = 2*MPAD)
  dim3 gg(2 * MPAD / 128, DH / 128);
  k_gemm_bt<<<gg, 256, 0, stream>>>(Abf, Wbf, XW);

  // combined SpMM + full fused epilogue
  k_spmm_fused<<<N_NODES / 4, 256, 0, stream>>>(row_ptr, ecol, eval,
                                                XW, XW + (size_t)MPAD * DH,
                                                b1, Wt, bt, S, exppart, augpart, scal + 0);

  // graph stats on assignments
  k_cs<<<64, 256, 0, stream>>>(S, scal + 18);
  k_edge<<<256, 256, 0, stream>>>(grow, gcol, gvals, S, scal + 2, scal + 1);

  // final scalar
  k_final<<<1, 256, 0, stream>>>(exppart, augpart, scal, (float*)d_out);
}